// Round 12
// baseline (845.656 us; speedup 1.0000x reference)
//
#include <hip/hip_runtime.h>
#include <hip/hip_fp16.h>

typedef _Float16 f16x2 __attribute__((ext_vector_type(2)));
typedef _Float16 half8 __attribute__((ext_vector_type(8)));

#define TS  512
#define HID 256
#define G3  768
#define EMB 128
#define RPB 96    // rows per xi1-stage block
#define CTL 767   // poller/publisher thread
#define BSZ 8     // handshake batch (steps) — r24's BSZ=4 cost ~11us, reverted
#define WAITN 8   // producers per batch (xi0 blocks / xi1 blocks)

__device__ __forceinline__ float sigmoidf_(float x){ return 1.0f/(1.0f+__expf(-x)); }
__device__ __forceinline__ float tanhf_(float x){
  float e = __expf(-2.0f*fabsf(x));
  float t = (1.0f-e)/(1.0f+e);
  return copysignf(t,x);
}

// ---------------- fully-fused pipeline (1 kernel, 18 blocks) ----------------
// ROUND-25: r24 A/B decomposition — logits fusion saved ~8us of dispatch
// overhead but BSZ 8->4 cost ~11us (2x CTL fence+poll rounds + 2x publish
// fences = ~21 cy/step serial sync). Net wash. This round: revert BSZ to 8,
// KEEP logits fusion — the only change vs r24. Expected pipe ~752-757
// (r23's 750 + 4us logits tail), total ~824-832.
// Rec step itself is structurally walled (rounds 13-22: grant = half-RF/wg
// 84@12w/128@8w/236@4w; all feed mixes at >=8 waves land 3350-3540 cy/step;
// 4-wave all-resident 6620 via exposed latency) — byte-identical to r23.
// Decision rule: if total >= 836, composition space is exhausted -> ROOFLINE.
#define SHUF(V,A,B) __builtin_shufflevector(V,V,A,B)
#define WR32(X) X(0,0) X(0,1) X(0,2) X(0,3) X(1,0) X(1,1) X(1,2) X(1,3) \
                X(2,0) X(2,1) X(2,2) X(2,3) X(3,0) X(3,1) X(3,2) X(3,3) \
                X(4,0) X(4,1) X(4,2) X(4,3) X(5,0) X(5,1) X(5,2) X(5,3) \
                X(6,0) X(6,1) X(6,2) X(6,3) X(7,0) X(7,1) X(7,2) X(7,3)

template<int MODE>  // 0 = layer 1 (waits cntX, publishes flagB), 1 = layer 2 (waits cntB)
__device__ __forceinline__ void rec_layer(const float* __restrict__ Whh,
    const float* __restrict__ bhh, const float* __restrict__ xi,
    _Float16* __restrict__ h16out, float* __restrict__ f32out,
    unsigned* __restrict__ flagB, unsigned* __restrict__ cntWait,
    _Float16 (*hbuf)[8*40], float* gh, float* bhhL,
    const float* __restrict__ Wout, const float* __restrict__ bout,
    float* __restrict__ out)
{
  int tid = threadIdx.x;
  int g   = tid >> 3;        // 0..95 : rows 8g..8g+7
  int o   = tid & 7;         // col chunk [32o, 32o+32)

#define WDECL(I,C) half8 w##I##_##C;
  WR32(WDECL)
#define WLOAD(I,C) { \
    const float4* p_ = (const float4*)(Whh + (long)(8*g+(I))*HID + 32*o + 8*(C)); \
    float4 u_ = p_[0], v_ = p_[1]; \
    w##I##_##C = (half8){(_Float16)u_.x,(_Float16)u_.y,(_Float16)u_.z,(_Float16)u_.w, \
                         (_Float16)v_.x,(_Float16)v_.y,(_Float16)v_.z,(_Float16)v_.w}; }
  WR32(WLOAD)

  float hprev = 0.f;
  float xr=0.f, xz=0.f, xn=0.f;
  bhhL[tid] = bhh[tid];                       // biases live in LDS
  if (tid < 80) ((half8*)hbuf)[tid] = (half8)(_Float16)0;  // zero both buffers

  if (tid == CTL){   // wait for batch 0 of this layer's xi
    while (__hip_atomic_load(&cntWait[0], __ATOMIC_RELAXED, __HIP_MEMORY_SCOPE_AGENT) < WAITN)
      __builtin_amdgcn_s_sleep(1);
    __threadfence();
  }
  __syncthreads();
  if (tid < HID){  // xi for t=0 (safe: batch 0 confirmed above)
    xr = xi[tid]; xz = xi[HID+tid]; xn = xi[2*HID+tid];
  }

  for (int t = 0; t < TS; t++){
    // at the last step of a batch, confirm the NEXT batch so the
    // elementwise-phase prefetch of xi[t+1] is safe.
    if (tid == CTL && ((t+1) & (BSZ-1)) == 0 && t+1 < TS){
      unsigned b = (unsigned)(t+1) / BSZ;
      while (__hip_atomic_load(&cntWait[b], __ATOMIC_RELAXED, __HIP_MEMORY_SCOPE_AGENT) < WAITN)
        __builtin_amdgcn_s_sleep(1);
      __threadfence();
    }

    // ---- dot phase: 4 h-chunk reads, 128 fdot2, accs a0..a7 ----
    const half8* hp = (const half8*)(&hbuf[t & 1][o*40]);
    float a0=0.f,a1=0.f,a2=0.f,a3=0.f,a4=0.f,a5=0.f,a6=0.f,a7=0.f;
#define DOT1(I,C,HV) \
    a##I = __builtin_amdgcn_fdot2(SHUF(w##I##_##C,0,1), SHUF(HV,0,1), a##I, false); \
    a##I = __builtin_amdgcn_fdot2(SHUF(w##I##_##C,2,3), SHUF(HV,2,3), a##I, false); \
    a##I = __builtin_amdgcn_fdot2(SHUF(w##I##_##C,4,5), SHUF(HV,4,5), a##I, false); \
    a##I = __builtin_amdgcn_fdot2(SHUF(w##I##_##C,6,7), SHUF(HV,6,7), a##I, false);
#define DOTCHUNK(C) { half8 hv = hp[C]; \
    DOT1(0,C,hv) DOT1(1,C,hv) DOT1(2,C,hv) DOT1(3,C,hv) \
    DOT1(4,C,hv) DOT1(5,C,hv) DOT1(6,C,hv) DOT1(7,C,hv) }
    DOTCHUNK(0) DOTCHUNK(1) DOTCHUNK(2) DOTCHUNK(3)

    // ---- 8-lane butterfly; lane o ends with full dot of row 8g+o == tid ----
    bool b0 = o & 1, b1 = o & 2, b2 = o & 4;
    float s, r_;
    s = b0 ? a0 : a1; r_ = __shfl_xor(s, 1, 64); float c0 = (b0 ? a1 : a0) + r_;
    s = b0 ? a2 : a3; r_ = __shfl_xor(s, 1, 64); float c1 = (b0 ? a3 : a2) + r_;
    s = b0 ? a4 : a5; r_ = __shfl_xor(s, 1, 64); float c2 = (b0 ? a5 : a4) + r_;
    s = b0 ? a6 : a7; r_ = __shfl_xor(s, 1, 64); float c3 = (b0 ? a7 : a6) + r_;
    s = b1 ? c0 : c1; r_ = __shfl_xor(s, 2, 64); float d0 = (b1 ? c1 : c0) + r_;
    s = b1 ? c2 : c3; r_ = __shfl_xor(s, 2, 64); float d1 = (b1 ? c3 : c2) + r_;
    s = b2 ? d0 : d1; r_ = __shfl_xor(s, 4, 64); float e  = (b2 ? d1 : d0) + r_;
    gh[tid] = e;
    __syncthreads();

    // ---- elementwise phase: unit j = tid < 256 ----
    if (tid < HID){
      float r = sigmoidf_(xr + bhhL[tid] + gh[tid]);
      float z = sigmoidf_(xz + bhhL[HID+tid] + gh[HID+tid]);
      float n = tanhf_(xn + r*(gh[2*HID+tid] + bhhL[2*HID+tid]));
      float hnew = (1.0f - z)*n + z*hprev;
      hprev = hnew;
      if (MODE == 1) f32out[(long)t*HID + tid] = hnew;
      float partner = __shfl_xor(hnew, 1, 64);
      if ((tid & 1) == 0){
        f16x2 p; p.x = (_Float16)hnew; p.y = (_Float16)partner;
        *(f16x2*)(&hbuf[(t+1)&1][(tid>>5)*40 + (tid&31)]) = p;
        if (MODE == 0) *(f16x2*)(h16out + (long)t*HID + tid) = p;
      }
      if (t+1 < TS){  // prefetch xi[t+1]; latency rides under next dot phase
        const float* xp = xi + (long)(t+1)*G3;
        xr = xp[tid]; xz = xp[HID+tid]; xn = xp[2*HID+tid];
      }
    }
    __syncthreads();
    // layer-1: publish once per batch
    if (MODE == 0 && tid == CTL && ((t+1) & (BSZ-1)) == 0){
      __threadfence();
      __hip_atomic_store(&flagB[t / BSZ], 1u, __ATOMIC_RELEASE, __HIP_MEMORY_SCOPE_AGENT);
    }
  }

  // ---- layer-2 tail: logits fused (starts the instant the rec finishes) ----
  if (MODE == 1){
    __syncthreads();   // drains f32out stores (vmcnt) block-wide
    for (int i = tid; i < 2*TS; i += 768){
      int t = i >> 1, c = i & 1;
      const float4* hr = (const float4*)(f32out + (long)t*HID);
      const float4* wr = (const float4*)(Wout + c*HID);
      float acc = bout[c];
      #pragma unroll 8
      for (int m = 0; m < HID/4; m++){
        float4 h = hr[m]; float4 wv = wr[m];
        acc += h.x*wv.x + h.y*wv.y + h.z*wv.z + h.w*wv.w;
      }
      out[i] = acc;
    }
  }
}

__device__ __forceinline__ void xi1_stage(const float* __restrict__ Wih1,
    const float* __restrict__ bih1, const _Float16* __restrict__ h16,
    float* __restrict__ xi1, unsigned* __restrict__ flagB,
    unsigned* __restrict__ cntB, int slice)
{
  int tid = threadIdx.x;
  int r = tid >> 3, o = tid & 7;        // row r of slice; cols [32o,32o+32)
  int row = slice*RPB + r;
  half8 w0,w1,w2,w3;                    // 16 VGPRs, register-resident slice
  {
    const float4* wp = (const float4*)(Wih1 + (long)row*HID + o*32);
    float4 p0=wp[0],p1=wp[1],p2=wp[2],p3=wp[3],p4=wp[4],p5=wp[5],p6=wp[6],p7=wp[7];
    w0 = (half8){(_Float16)p0.x,(_Float16)p0.y,(_Float16)p0.z,(_Float16)p0.w,
                 (_Float16)p1.x,(_Float16)p1.y,(_Float16)p1.z,(_Float16)p1.w};
    w1 = (half8){(_Float16)p2.x,(_Float16)p2.y,(_Float16)p2.z,(_Float16)p2.w,
                 (_Float16)p3.x,(_Float16)p3.y,(_Float16)p3.z,(_Float16)p3.w};
    w2 = (half8){(_Float16)p4.x,(_Float16)p4.y,(_Float16)p4.z,(_Float16)p4.w,
                 (_Float16)p5.x,(_Float16)p5.y,(_Float16)p5.z,(_Float16)p5.w};
    w3 = (half8){(_Float16)p6.x,(_Float16)p6.y,(_Float16)p6.z,(_Float16)p6.w,
                 (_Float16)p7.x,(_Float16)p7.y,(_Float16)p7.z,(_Float16)p7.w};
  }
  float bias = bih1[row];

  for (int b = 0; b < TS/BSZ; b++){
    if (tid == 0){
      while (__hip_atomic_load(&flagB[b], __ATOMIC_RELAXED, __HIP_MEMORY_SCOPE_AGENT) == 0u)
        __builtin_amdgcn_s_sleep(1);
      __threadfence();
    }
    __syncthreads();
    #pragma unroll
    for (int u = 0; u < BSZ; u++){
      int t = b*BSZ + u;
      const half8* hp = (const half8*)(h16 + (long)t*HID + o*32);
      half8 h0 = hp[0], h1 = hp[1], h2 = hp[2], h3 = hp[3];
      float acc = 0.f;
#define XDOT(W,H) \
      acc = __builtin_amdgcn_fdot2(SHUF(W,0,1), SHUF(H,0,1), acc, false); \
      acc = __builtin_amdgcn_fdot2(SHUF(W,2,3), SHUF(H,2,3), acc, false); \
      acc = __builtin_amdgcn_fdot2(SHUF(W,4,5), SHUF(H,4,5), acc, false); \
      acc = __builtin_amdgcn_fdot2(SHUF(W,6,7), SHUF(H,6,7), acc, false);
      XDOT(w0,h0) XDOT(w1,h1) XDOT(w2,h2) XDOT(w3,h3)
      acc += __shfl_xor(acc, 1, 64);
      acc += __shfl_xor(acc, 2, 64);
      acc += __shfl_xor(acc, 4, 64);
      if (o == 0) xi1[(long)t*G3 + row] = acc + bias;
    }
    __syncthreads();   // drains each thread's stores (vmcnt) before fence
    if (tid == 0){
      __threadfence();
      atomicAdd(&cntB[b], 1u);
    }
  }
}

// xi0 producer: slice owns 96 rows of Wih0; weights register-resident
// (16 f32/thread); emb row staged in pad-swizzled LDS (broadcast reads,
// conflict-free). Publishes BSZ-step batches via cntX.
__device__ __forceinline__ void xi0_stage(const int* __restrict__ x,
    const float* __restrict__ emb_tab, const float* __restrict__ Wih0,
    const float* __restrict__ bih0, float* __restrict__ xi0,
    unsigned* __restrict__ cntX, int slice, float* embp)
{
  int tid = threadIdx.x;
  int j = tid >> 3, kk = tid & 7;       // output row j of slice; 16-col chunk kk
  int row = slice*96 + j;
  float w16[16];
  {
    const float4* wp = (const float4*)(Wih0 + (long)row*EMB + kk*16);
    float4 a = wp[0], b = wp[1], c = wp[2], d = wp[3];
    w16[0]=a.x;  w16[1]=a.y;  w16[2]=a.z;  w16[3]=a.w;
    w16[4]=b.x;  w16[5]=b.y;  w16[6]=b.z;  w16[7]=b.w;
    w16[8]=c.x;  w16[9]=c.y;  w16[10]=c.z; w16[11]=c.w;
    w16[12]=d.x; w16[13]=d.y; w16[14]=d.z; w16[15]=d.w;
  }
  float bias = bih0[row];

  for (int t = 0; t < TS; t++){
    if (tid < EMB){
      int idx = x[(long)t*512 + 511];
      embp[tid + (tid >> 4)] = emb_tab[(long)idx*EMB + tid];
    }
    __syncthreads();
    float a = 0.f;
    #pragma unroll
    for (int m = 0; m < 16; m++) a += w16[m] * embp[kk*17 + m];
    a += __shfl_xor(a, 1, 64);
    a += __shfl_xor(a, 2, 64);
    a += __shfl_xor(a, 4, 64);
    if (kk == 0) xi0[(long)t*G3 + row] = a + bias;
    __syncthreads();   // protects embp reuse + drains stores before fence
    if (((t+1) & (BSZ-1)) == 0 && tid == 0){
      __threadfence();
      atomicAdd(&cntX[t / BSZ], 1u);
    }
  }
}

__global__ __launch_bounds__(768, 3)
void pipe_kernel(
    const float* __restrict__ Whh0, const float* __restrict__ bhh0,
    const float* __restrict__ Wih1, const float* __restrict__ bih1,
    const float* __restrict__ Whh1, const float* __restrict__ bhh1,
    const int* __restrict__ x, const float* __restrict__ emb_tab,
    const float* __restrict__ Wih0, const float* __restrict__ bih0,
    const float* __restrict__ Wout, const float* __restrict__ bout,
    float* __restrict__ xi0, _Float16* __restrict__ h1f16,
    float* __restrict__ xi1, float* __restrict__ h2,
    float* __restrict__ out,
    unsigned* __restrict__ flagB, unsigned* __restrict__ cntB,
    unsigned* __restrict__ cntX)
{
  __shared__ __align__(16) _Float16 hbuf[2][8*40];   // 1280 B
  __shared__ float gh[G3];                           // 3072 B
  __shared__ float bhhL[G3];                         // 3072 B
  __shared__ float embp[136];                        // 544 B (pad-swizzled)
  int bid = blockIdx.x;
  if (bid == 0)
    rec_layer<0>(Whh0, bhh0, xi0, h1f16, nullptr, flagB, cntX, hbuf, gh, bhhL,
                 nullptr, nullptr, nullptr);
  else if (bid == 9)
    rec_layer<1>(Whh1, bhh1, xi1, nullptr, h2, flagB, cntB, hbuf, gh, bhhL,
                 Wout, bout, out);
  else if (bid < 9)
    xi1_stage(Wih1, bih1, h1f16, xi1, flagB, cntB, bid - 1);
  else
    xi0_stage(x, emb_tab, Wih0, bih0, xi0, cntX, bid - 10, embp);
}

extern "C" void kernel_launch(void* const* d_in, const int* in_sizes, int n_in,
                              void* d_out, int out_size, void* d_ws, size_t ws_size,
                              hipStream_t stream)
{
  const int*   x    = (const int*)  d_in[0];
  const float* emb  = (const float*)d_in[1];
  const float* Wih0 = (const float*)d_in[2];
  const float* Whh0 = (const float*)d_in[3];
  const float* bih0 = (const float*)d_in[4];
  const float* bhh0 = (const float*)d_in[5];
  const float* Wih1 = (const float*)d_in[6];
  const float* Whh1 = (const float*)d_in[7];
  const float* bih1 = (const float*)d_in[8];
  const float* bhh1 = (const float*)d_in[9];
  const float* Wout = (const float*)d_in[10];
  const float* bout = (const float*)d_in[11];
  float* out = (float*)d_out;

  char* ws = (char*)d_ws;
  float*     xi0   = (float*)(ws);                       // 512*768 f32 = 1.5 MB
  float*     xi1   = (float*)(ws + 1572864);             // 512*768 f32 = 1.5 MB
  _Float16*  h1f16 = (_Float16*)(ws + 3145728);          // 512*256 f16 = 256 KB
  float*     h2    = (float*)(ws + 3407872);             // 512*256 f32 = 512 KB
  unsigned*  flagB = (unsigned*)(ws + 3932160);          // 64 u32
  unsigned*  cntB  = (unsigned*)(ws + 3933184);          // 64 u32
  unsigned*  cntX  = (unsigned*)(ws + 3934208);          // 64 u32

  hipMemsetAsync(ws + 3932160, 0, 4096, stream);
  pipe_kernel<<<18, 768, 0, stream>>>(Whh0, bhh0, Wih1, bih1, Whh1, bhh1,
                                      x, emb, Wih0, bih0, Wout, bout,
                                      xi0, h1f16, xi1, h2, out,
                                      flagB, cntB, cntX);
}

// Round 13
// 833.724 us; speedup vs baseline: 1.0143x; 1.0143x over previous
//
#include <hip/hip_runtime.h>
#include <hip/hip_fp16.h>

typedef _Float16 f16x2 __attribute__((ext_vector_type(2)));
typedef _Float16 half8 __attribute__((ext_vector_type(8)));

#define TS  512
#define HID 256
#define G3  768
#define EMB 128
#define NB1 8
#define RPB 96    // rows per xi1-stage block
#define CTL 767   // poller/publisher thread
#define BSZ 8     // handshake batch (steps)
#define WAITN 8   // producers per batch (xi0 blocks / xi1 blocks)

__device__ __forceinline__ float sigmoidf_(float x){ return 1.0f/(1.0f+__expf(-x)); }
__device__ __forceinline__ float tanhf_(float x){
  float e = __expf(-2.0f*fabsf(x));
  float t = (1.0f-e)/(1.0f+e);
  return copysignf(t,x);
}

// ---------------- fully-fused pipeline (1 kernel, 18 blocks) ----------------
// ROUND-26: restore the session-best r23 artifact byte-for-byte (836.2 us).
// A/B ledger across r23/r24/r25: separate-logits/BSZ8 = 836.2 (best);
// fused-logits/BSZ4 = 839.5; fused-logits/BSZ8 = 845.7 — the logits fusion
// is net-negative (~+15us pipe for ~8us dispatch saved) and BSZ4/8 is a
// wash under fusion. Rec step is structurally walled (rounds 13-22: VGPR
// grant = half-RF/wg at every wave count — 84@12w/128@8w/236@4w, immune to
// all attributes/LDS/AGPR levers; every weight-feed mix at >=8 waves lands
// 3350-3540 cy/step = sum of DS+VMEM port times for ~190 KB/step off-reg
// weights; 4-wave all-resident = 6620 cy via exposed latency; cross-CU
// split = 6050 via handshake). Composition space exhausted (r23-r25).
// If this reproduces ~836 +/- noise: ROOFLINE (serialization-bound floor:
// ~715us rec wall + fill + fixed harness overhead).
#define SHUF(V,A,B) __builtin_shufflevector(V,V,A,B)
#define WR32(X) X(0,0) X(0,1) X(0,2) X(0,3) X(1,0) X(1,1) X(1,2) X(1,3) \
                X(2,0) X(2,1) X(2,2) X(2,3) X(3,0) X(3,1) X(3,2) X(3,3) \
                X(4,0) X(4,1) X(4,2) X(4,3) X(5,0) X(5,1) X(5,2) X(5,3) \
                X(6,0) X(6,1) X(6,2) X(6,3) X(7,0) X(7,1) X(7,2) X(7,3)

template<int MODE>  // 0 = layer 1 (waits cntX, publishes flagB), 1 = layer 2 (waits cntB)
__device__ __forceinline__ void rec_layer(const float* __restrict__ Whh,
    const float* __restrict__ bhh, const float* __restrict__ xi,
    _Float16* __restrict__ h16out, float* __restrict__ f32out,
    unsigned* __restrict__ flagB, unsigned* __restrict__ cntWait,
    _Float16 (*hbuf)[8*40], float* gh, float* bhhL)
{
  int tid = threadIdx.x;
  int g   = tid >> 3;        // 0..95 : rows 8g..8g+7
  int o   = tid & 7;         // col chunk [32o, 32o+32)

#define WDECL(I,C) half8 w##I##_##C;
  WR32(WDECL)
#define WLOAD(I,C) { \
    const float4* p_ = (const float4*)(Whh + (long)(8*g+(I))*HID + 32*o + 8*(C)); \
    float4 u_ = p_[0], v_ = p_[1]; \
    w##I##_##C = (half8){(_Float16)u_.x,(_Float16)u_.y,(_Float16)u_.z,(_Float16)u_.w, \
                         (_Float16)v_.x,(_Float16)v_.y,(_Float16)v_.z,(_Float16)v_.w}; }
  WR32(WLOAD)

  float hprev = 0.f;
  float xr=0.f, xz=0.f, xn=0.f;
  bhhL[tid] = bhh[tid];                       // biases live in LDS
  if (tid < 80) ((half8*)hbuf)[tid] = (half8)(_Float16)0;  // zero both buffers

  if (tid == CTL){   // wait for batch 0 of this layer's xi
    while (__hip_atomic_load(&cntWait[0], __ATOMIC_RELAXED, __HIP_MEMORY_SCOPE_AGENT) < WAITN)
      __builtin_amdgcn_s_sleep(1);
    __threadfence();
  }
  __syncthreads();
  if (tid < HID){  // xi for t=0 (safe: batch 0 confirmed above)
    xr = xi[tid]; xz = xi[HID+tid]; xn = xi[2*HID+tid];
  }

  for (int t = 0; t < TS; t++){
    // at the last step of a batch, confirm the NEXT batch so the
    // elementwise-phase prefetch of xi[t+1] is safe.
    if (tid == CTL && ((t+1) & (BSZ-1)) == 0 && t+1 < TS){
      unsigned b = (unsigned)(t+1) >> 3;
      while (__hip_atomic_load(&cntWait[b], __ATOMIC_RELAXED, __HIP_MEMORY_SCOPE_AGENT) < WAITN)
        __builtin_amdgcn_s_sleep(1);
      __threadfence();
    }

    // ---- dot phase: 4 h-chunk reads, 128 fdot2, accs a0..a7 ----
    const half8* hp = (const half8*)(&hbuf[t & 1][o*40]);
    float a0=0.f,a1=0.f,a2=0.f,a3=0.f,a4=0.f,a5=0.f,a6=0.f,a7=0.f;
#define DOT1(I,C,HV) \
    a##I = __builtin_amdgcn_fdot2(SHUF(w##I##_##C,0,1), SHUF(HV,0,1), a##I, false); \
    a##I = __builtin_amdgcn_fdot2(SHUF(w##I##_##C,2,3), SHUF(HV,2,3), a##I, false); \
    a##I = __builtin_amdgcn_fdot2(SHUF(w##I##_##C,4,5), SHUF(HV,4,5), a##I, false); \
    a##I = __builtin_amdgcn_fdot2(SHUF(w##I##_##C,6,7), SHUF(HV,6,7), a##I, false);
#define DOTCHUNK(C) { half8 hv = hp[C]; \
    DOT1(0,C,hv) DOT1(1,C,hv) DOT1(2,C,hv) DOT1(3,C,hv) \
    DOT1(4,C,hv) DOT1(5,C,hv) DOT1(6,C,hv) DOT1(7,C,hv) }
    DOTCHUNK(0) DOTCHUNK(1) DOTCHUNK(2) DOTCHUNK(3)

    // ---- 8-lane butterfly; lane o ends with full dot of row 8g+o == tid ----
    bool b0 = o & 1, b1 = o & 2, b2 = o & 4;
    float s, r_;
    s = b0 ? a0 : a1; r_ = __shfl_xor(s, 1, 64); float c0 = (b0 ? a1 : a0) + r_;
    s = b0 ? a2 : a3; r_ = __shfl_xor(s, 1, 64); float c1 = (b0 ? a3 : a2) + r_;
    s = b0 ? a4 : a5; r_ = __shfl_xor(s, 1, 64); float c2 = (b0 ? a5 : a4) + r_;
    s = b0 ? a6 : a7; r_ = __shfl_xor(s, 1, 64); float c3 = (b0 ? a7 : a6) + r_;
    s = b1 ? c0 : c1; r_ = __shfl_xor(s, 2, 64); float d0 = (b1 ? c1 : c0) + r_;
    s = b1 ? c2 : c3; r_ = __shfl_xor(s, 2, 64); float d1 = (b1 ? c3 : c2) + r_;
    s = b2 ? d0 : d1; r_ = __shfl_xor(s, 4, 64); float e  = (b2 ? d1 : d0) + r_;
    gh[tid] = e;
    __syncthreads();

    // ---- elementwise phase: unit j = tid < 256 ----
    if (tid < HID){
      float r = sigmoidf_(xr + bhhL[tid] + gh[tid]);
      float z = sigmoidf_(xz + bhhL[HID+tid] + gh[HID+tid]);
      float n = tanhf_(xn + r*(gh[2*HID+tid] + bhhL[2*HID+tid]));
      float hnew = (1.0f - z)*n + z*hprev;
      hprev = hnew;
      if (MODE == 1) f32out[(long)t*HID + tid] = hnew;
      float partner = __shfl_xor(hnew, 1, 64);
      if ((tid & 1) == 0){
        f16x2 p; p.x = (_Float16)hnew; p.y = (_Float16)partner;
        *(f16x2*)(&hbuf[(t+1)&1][(tid>>5)*40 + (tid&31)]) = p;
        if (MODE == 0) *(f16x2*)(h16out + (long)t*HID + tid) = p;
      }
      if (t+1 < TS){  // prefetch xi[t+1]; latency rides under next dot phase
        const float* xp = xi + (long)(t+1)*G3;
        xr = xp[tid]; xz = xp[HID+tid]; xn = xp[2*HID+tid];
      }
    }
    __syncthreads();
    // layer-1: publish once per batch
    if (MODE == 0 && tid == CTL && ((t+1) & (BSZ-1)) == 0){
      __threadfence();
      __hip_atomic_store(&flagB[t >> 3], 1u, __ATOMIC_RELEASE, __HIP_MEMORY_SCOPE_AGENT);
    }
  }
}

__device__ __forceinline__ void xi1_stage(const float* __restrict__ Wih1,
    const float* __restrict__ bih1, const _Float16* __restrict__ h16,
    float* __restrict__ xi1, unsigned* __restrict__ flagB,
    unsigned* __restrict__ cntB, int slice)
{
  int tid = threadIdx.x;
  int r = tid >> 3, o = tid & 7;        // row r of slice; cols [32o,32o+32)
  int row = slice*RPB + r;
  half8 w0,w1,w2,w3;                    // 16 VGPRs, register-resident slice
  {
    const float4* wp = (const float4*)(Wih1 + (long)row*HID + o*32);
    float4 p0=wp[0],p1=wp[1],p2=wp[2],p3=wp[3],p4=wp[4],p5=wp[5],p6=wp[6],p7=wp[7];
    w0 = (half8){(_Float16)p0.x,(_Float16)p0.y,(_Float16)p0.z,(_Float16)p0.w,
                 (_Float16)p1.x,(_Float16)p1.y,(_Float16)p1.z,(_Float16)p1.w};
    w1 = (half8){(_Float16)p2.x,(_Float16)p2.y,(_Float16)p2.z,(_Float16)p2.w,
                 (_Float16)p3.x,(_Float16)p3.y,(_Float16)p3.z,(_Float16)p3.w};
    w2 = (half8){(_Float16)p4.x,(_Float16)p4.y,(_Float16)p4.z,(_Float16)p4.w,
                 (_Float16)p5.x,(_Float16)p5.y,(_Float16)p5.z,(_Float16)p5.w};
    w3 = (half8){(_Float16)p6.x,(_Float16)p6.y,(_Float16)p6.z,(_Float16)p6.w,
                 (_Float16)p7.x,(_Float16)p7.y,(_Float16)p7.z,(_Float16)p7.w};
  }
  float bias = bih1[row];

  for (int b = 0; b < TS/BSZ; b++){
    if (tid == 0){
      while (__hip_atomic_load(&flagB[b], __ATOMIC_RELAXED, __HIP_MEMORY_SCOPE_AGENT) == 0u)
        __builtin_amdgcn_s_sleep(1);
      __threadfence();
    }
    __syncthreads();
    #pragma unroll 4
    for (int u = 0; u < BSZ; u++){
      int t = b*BSZ + u;
      const half8* hp = (const half8*)(h16 + (long)t*HID + o*32);
      half8 h0 = hp[0], h1 = hp[1], h2 = hp[2], h3 = hp[3];
      float acc = 0.f;
#define XDOT(W,H) \
      acc = __builtin_amdgcn_fdot2(SHUF(W,0,1), SHUF(H,0,1), acc, false); \
      acc = __builtin_amdgcn_fdot2(SHUF(W,2,3), SHUF(H,2,3), acc, false); \
      acc = __builtin_amdgcn_fdot2(SHUF(W,4,5), SHUF(H,4,5), acc, false); \
      acc = __builtin_amdgcn_fdot2(SHUF(W,6,7), SHUF(H,6,7), acc, false);
      XDOT(w0,h0) XDOT(w1,h1) XDOT(w2,h2) XDOT(w3,h3)
      acc += __shfl_xor(acc, 1, 64);
      acc += __shfl_xor(acc, 2, 64);
      acc += __shfl_xor(acc, 4, 64);
      if (o == 0) xi1[(long)t*G3 + row] = acc + bias;
    }
    __syncthreads();   // drains each thread's stores (vmcnt) before fence
    if (tid == 0){
      __threadfence();
      atomicAdd(&cntB[b], 1u);
    }
  }
}

// xi0 producer: slice owns 96 rows of Wih0; weights register-resident
// (16 f32/thread); emb row staged in pad-swizzled LDS (broadcast reads,
// conflict-free: bank = 17*kk mod 32, 8 distinct banks, same-addr within
// each 8-lane j-group). Publishes 8-step batches via cntX (same pattern
// as xi1_stage -> cntB).
__device__ __forceinline__ void xi0_stage(const int* __restrict__ x,
    const float* __restrict__ emb_tab, const float* __restrict__ Wih0,
    const float* __restrict__ bih0, float* __restrict__ xi0,
    unsigned* __restrict__ cntX, int slice, float* embp)
{
  int tid = threadIdx.x;
  int j = tid >> 3, kk = tid & 7;       // output row j of slice; 16-col chunk kk
  int row = slice*96 + j;
  float w16[16];
  {
    const float4* wp = (const float4*)(Wih0 + (long)row*EMB + kk*16);
    float4 a = wp[0], b = wp[1], c = wp[2], d = wp[3];
    w16[0]=a.x;  w16[1]=a.y;  w16[2]=a.z;  w16[3]=a.w;
    w16[4]=b.x;  w16[5]=b.y;  w16[6]=b.z;  w16[7]=b.w;
    w16[8]=c.x;  w16[9]=c.y;  w16[10]=c.z; w16[11]=c.w;
    w16[12]=d.x; w16[13]=d.y; w16[14]=d.z; w16[15]=d.w;
  }
  float bias = bih0[row];

  for (int t = 0; t < TS; t++){
    if (tid < EMB){
      int idx = x[(long)t*512 + 511];
      embp[tid + (tid >> 4)] = emb_tab[(long)idx*EMB + tid];
    }
    __syncthreads();
    float a = 0.f;
    #pragma unroll
    for (int m = 0; m < 16; m++) a += w16[m] * embp[kk*17 + m];
    a += __shfl_xor(a, 1, 64);
    a += __shfl_xor(a, 2, 64);
    a += __shfl_xor(a, 4, 64);
    if (kk == 0) xi0[(long)t*G3 + row] = a + bias;
    __syncthreads();   // protects embp reuse + drains stores before fence
    if (((t+1) & (BSZ-1)) == 0 && tid == 0){
      __threadfence();
      atomicAdd(&cntX[t >> 3], 1u);
    }
  }
}

__global__ __launch_bounds__(768, 3)
void pipe_kernel(
    const float* __restrict__ Whh0, const float* __restrict__ bhh0,
    const float* __restrict__ Wih1, const float* __restrict__ bih1,
    const float* __restrict__ Whh1, const float* __restrict__ bhh1,
    const int* __restrict__ x, const float* __restrict__ emb_tab,
    const float* __restrict__ Wih0, const float* __restrict__ bih0,
    float* __restrict__ xi0, _Float16* __restrict__ h1f16,
    float* __restrict__ xi1, float* __restrict__ h2,
    unsigned* __restrict__ flagB, unsigned* __restrict__ cntB,
    unsigned* __restrict__ cntX)
{
  __shared__ __align__(16) _Float16 hbuf[2][8*40];   // 1280 B
  __shared__ float gh[G3];                           // 3072 B
  __shared__ float bhhL[G3];                         // 3072 B
  __shared__ float embp[136];                        // 544 B (pad-swizzled)
  int bid = blockIdx.x;
  if (bid == 0)
    rec_layer<0>(Whh0, bhh0, xi0, h1f16, nullptr, flagB, cntX, hbuf, gh, bhhL);
  else if (bid == 9)
    rec_layer<1>(Whh1, bhh1, xi1, nullptr, h2, flagB, cntB, hbuf, gh, bhhL);
  else if (bid < 9)
    xi1_stage(Wih1, bih1, h1f16, xi1, flagB, cntB, bid - 1);
  else
    xi0_stage(x, emb_tab, Wih0, bih0, xi0, cntX, bid - 10, embp);
}

// K5: logits[t][c] = b_out[c] + sum_i h2[t][i] * W_out[c][i]
__global__ __launch_bounds__(1024) void logits_kernel(const float* __restrict__ h2,
    const float* __restrict__ Wout, const float* __restrict__ bout,
    float* __restrict__ out)
{
  __shared__ __align__(16) float wsm[2*HID];
  __shared__ float bs[2];
  int tid = threadIdx.x;
  if (tid < 2*HID) wsm[tid] = Wout[tid];
  if (tid < 2)     bs[tid]  = bout[tid];
  __syncthreads();
  int t = tid >> 1, c = tid & 1;
  const float4* hr = (const float4*)(h2 + (long)t*HID);
  const float4* wr = (const float4*)(wsm + c*HID);
  float acc = bs[c];
  #pragma unroll 8
  for (int m=0;m<HID/4;m++){
    float4 h = hr[m]; float4 wv = wr[m];
    acc += h.x*wv.x + h.y*wv.y + h.z*wv.z + h.w*wv.w;
  }
  out[tid] = acc;
}

extern "C" void kernel_launch(void* const* d_in, const int* in_sizes, int n_in,
                              void* d_out, int out_size, void* d_ws, size_t ws_size,
                              hipStream_t stream)
{
  const int*   x    = (const int*)  d_in[0];
  const float* emb  = (const float*)d_in[1];
  const float* Wih0 = (const float*)d_in[2];
  const float* Whh0 = (const float*)d_in[3];
  const float* bih0 = (const float*)d_in[4];
  const float* bhh0 = (const float*)d_in[5];
  const float* Wih1 = (const float*)d_in[6];
  const float* Whh1 = (const float*)d_in[7];
  const float* bih1 = (const float*)d_in[8];
  const float* bhh1 = (const float*)d_in[9];
  const float* Wout = (const float*)d_in[10];
  const float* bout = (const float*)d_in[11];
  float* out = (float*)d_out;

  char* ws = (char*)d_ws;
  float*     xi0   = (float*)(ws);                       // 512*768 f32 = 1.5 MB
  float*     xi1   = (float*)(ws + 1572864);             // 512*768 f32 = 1.5 MB
  _Float16*  h1f16 = (_Float16*)(ws + 3145728);          // 512*256 f16 = 256 KB
  float*     h2    = (float*)(ws + 3407872);             // 512*256 f32 = 512 KB
  unsigned*  flagB = (unsigned*)(ws + 3932160);          // 64 u32
  unsigned*  cntB  = (unsigned*)(ws + 3933184);          // 64 u32
  unsigned*  cntX  = (unsigned*)(ws + 3934208);          // 64 u32

  hipMemsetAsync(ws + 3932160, 0, 4096, stream);
  pipe_kernel<<<18, 768, 0, stream>>>(Whh0, bhh0, Wih1, bih1, Whh1, bhh1,
                                      x, emb, Wih0, bih0,
                                      xi0, h1f16, xi1, h2, flagB, cntB, cntX);
  logits_kernel<<<1, 1024, 0, stream>>>(h2, Wout, bout, out);
}